// Round 11
// baseline (111.918 us; speedup 1.0000x reference)
//
#include <hip/hip_runtime.h>
#include <stdint.h>

typedef unsigned short u16;
typedef __attribute__((ext_vector_type(8))) short short8;   // 8 x bf16 fragment
typedef __attribute__((ext_vector_type(4))) float f32x4;
typedef __attribute__((ext_vector_type(16))) float f32x16;
typedef __attribute__((ext_vector_type(4))) unsigned short us4;
typedef __attribute__((ext_vector_type(4))) uint32_t u32x4;
typedef __attribute__((ext_vector_type(2))) int i32x2;
typedef __attribute__((ext_vector_type(4))) int i32x4;

#define MFMA(a,b,c)   __builtin_amdgcn_mfma_f32_16x16x32_bf16((a),(b),(c),0,0,0)
#define MFMA32(a,b,c) __builtin_amdgcn_mfma_f32_32x32x16_bf16((a),(b),(c),0,0,0)
#define L2E 1.44269504f

__device__ __forceinline__ u16 f2bf(float f){
    union { float f; uint32_t i; } v; v.f = f;
    uint32_t u = v.i;
    return (u16)((u + 0x7fffu + ((u >> 16) & 1u)) >> 16);
}
__device__ __forceinline__ uint32_t cvtpk(float lo, float hi){
    uint32_t r;
    asm("v_cvt_pk_bf16_f32 %0, %1, %2" : "=v"(r) : "v"(lo), "v"(hi));
    return r;
}
// barrier without the vmcnt(0) drain __syncthreads would emit
__device__ __forceinline__ void barrier_lgkm(){
    __builtin_amdgcn_sched_barrier(0);
    asm volatile("s_waitcnt lgkmcnt(0)" ::: "memory");
    __builtin_amdgcn_s_barrier();
    __builtin_amdgcn_sched_barrier(0);
}

// ---------------- workspace layout (bytes) ----------------
#define WS_W1T    0u           // [1536][512] bf16  rows: [Wq h0..7 | Wk | Wv] x d
#define WS_WOT    1572864u     // [8][64][64] bf16  (WoT[h][e'][e])
#define WS_WOUTT  1638400u     // [512][512] bf16   (WoutT[co][c])
#define WS_RELW   2162688u     // [8][63][64] bf16
#define WS_RELH   2227200u
#define WS_SCALE  2291712u     // [512] f32
#define WS_SHIFT  2293760u     // [512] f32
#define WS_Q      10684416u    // [64][1024][64] bf16 (pre-scaled by log2(e))
#define WS_K      19073024u
#define WS_VT     27461632u    // [64][64][1024] bf16 (Vt[bh][d][n])
#define WS_Z      52627456u    // [8192][512] bf16

// ================= K0: weight transposes + BN fold =================
__global__ __launch_bounds__(256) void k0_setup(
    const float* Wk, const float* Wq, const float* Wv, const float* Wo,
    const float* gamma, const float* beta, const float* mean, const float* var,
    const float* relw, const float* relh, const float* Wout,
    u16* W1T, u16* WoT, u16* WoutT,
    u16* RWbf, u16* RHbf, float* scaleZ, float* shiftZ)
{
    int idx = blockIdx.x * 256 + threadIdx.x;
    if (idx < 786432) {
        int co = idx >> 9, c = idx & 511;
        int p = co >> 9, rem = co & 511;
        int h = rem >> 6, d = rem & 63;
        const float* src = (p == 0) ? Wq : (p == 1) ? Wk : Wv;
        W1T[idx] = f2bf(src[h * 32768 + c * 64 + d]);
    } else if (idx < 819200) {
        int r = idx - 786432;
        int h = r >> 12; int e = (r & 4095) >> 6, ep = r & 63;
        WoT[h * 4096 + ep * 64 + e] = f2bf(Wo[h * 4096 + e * 64 + ep]);
    } else if (idx < 1081344) {
        int r = idx - 819200;
        int c = r >> 9, co = r & 511;
        WoutT[co * 512 + c] = f2bf(Wout[c * 512 + co]);
    } else if (idx < 1145856) {
        int r = idx - 1081344;
        if (r < 32256) RWbf[r] = f2bf(relw[r]);
        else           RHbf[r - 32256] = f2bf(relh[r - 32256]);
    } else if (idx < 1146368) {
        int ch = idx - 1145856;
        float sc = gamma[ch] * rsqrtf(var[ch] + 1e-3f);
        scaleZ[ch] = sc;
        shiftZ[ch] = beta[ch] - mean[ch] * sc;
    }
}

__device__ __forceinline__ void packA(u16* dst, f32x4 a0, f32x4 a1, f32x4 a2, f32x4 a3){
    u32x4 v0 = { cvtpk(a0.x,a0.y), cvtpk(a0.z,a0.w), cvtpk(a1.x,a1.y), cvtpk(a1.z,a1.w) };
    u32x4 v1 = { cvtpk(a2.x,a2.y), cvtpk(a2.z,a2.w), cvtpk(a3.x,a3.y), cvtpk(a3.z,a3.w) };
    *(u32x4*)dst = v0;
    *(u32x4*)(dst + 8) = v1;
}

// ================= K1: fused QKV projection GEMM (reads f32 x directly) =========
// grid: 768 (XCD-swizzled); nt: 0-3 Q, 4-7 K, 8-11 V; Q scaled by log2(e)
// A (x) staged via LDS (f32->bf16 pack); B (W1T) frags streamed DIRECT from L2.
__global__ __launch_bounds__(256, 3) void k1_gemm(
    const float* __restrict__ Xf, const u16* __restrict__ W1T,
    u16* Q, u16* K, u16* Vt)
{
    int s = blockIdx.x;
    int xcd = s & 7, r8 = s >> 3;
    int nt = r8 % 12, mt = (r8 / 12) * 8 + xcd;   // same-mt blocks share an XCD
    int tid = threadIdx.x;
    int w = tid >> 6, l = tid & 63, lg = l >> 4, ll = l & 15;
    int wm = w >> 1, wn = w & 1;
    int i0 = mt * 128, co0 = nt * 128;

    __shared__ __align__(16) u16 SM[20480];   // As[2][5120] | (epilogue Ts[128][136])
    u16* As = SM;

    int row = tid >> 1, c16 = (tid & 1) * 16;
    int st = row * 40 + c16;
    const float* ArowF = Xf + (size_t)(i0 + row) * 512 + c16;
    const u16*   Bg    = W1T + (size_t)(co0 + wn * 64 + ll) * 512 + lg * 8;

    f32x4 acc[4][4];
#pragma unroll
    for (int m = 0; m < 4; m++)
#pragma unroll
        for (int nn = 0; nn < 4; nn++) acc[m][nn] = (f32x4){0,0,0,0};

    f32x4 ra0 = *(const f32x4*)&ArowF[0];
    f32x4 ra1 = *(const f32x4*)&ArowF[4];
    f32x4 ra2 = *(const f32x4*)&ArowF[8];
    f32x4 ra3 = *(const f32x4*)&ArowF[12];
    short8 bnxt[4];
#pragma unroll
    for (int nn = 0; nn < 4; nn++)
        bnxt[nn] = *(const short8*)&Bg[nn * 8192];
    packA(&As[st], ra0, ra1, ra2, ra3);
    __syncthreads();
#pragma unroll
    for (int ks = 0; ks < 16; ++ks) {
        int cur = ks & 1, nxt = cur ^ 1;
        if (ks < 15) {
            ra0 = *(const f32x4*)&ArowF[(ks + 1) * 32];
            ra1 = *(const f32x4*)&ArowF[(ks + 1) * 32 + 4];
            ra2 = *(const f32x4*)&ArowF[(ks + 1) * 32 + 8];
            ra3 = *(const f32x4*)&ArowF[(ks + 1) * 32 + 12];
        }
        short8 bcur[4];
#pragma unroll
        for (int nn = 0; nn < 4; nn++) bcur[nn] = bnxt[nn];
        if (ks < 15) {
#pragma unroll
            for (int nn = 0; nn < 4; nn++)
                bnxt[nn] = *(const short8*)&Bg[nn * 8192 + (ks + 1) * 32];
        }
        const u16* Ab = As + cur * 5120;
        short8 af[4];
#pragma unroll
        for (int m = 0; m < 4; m++)
            af[m] = *(const short8*)&Ab[(wm * 64 + m * 16 + ll) * 40 + lg * 8];
#pragma unroll
        for (int m = 0; m < 4; m++)
#pragma unroll
            for (int nn = 0; nn < 4; nn++)
                acc[m][nn] = MFMA(af[m], bcur[nn], acc[m][nn]);
        if (ks < 15) packA(&As[nxt * 5120 + st], ra0, ra1, ra2, ra3);
        barrier_lgkm();    // lgkm-only: B prefetch loads stay in flight
    }

    int b = mt >> 3, nloc0 = (mt & 7) * 128;
    u16* Ts = SM;                        // [128][136] u16 = 34.8 KB
    if (nt < 8) {
        u16* dst = (nt < 4) ? Q : K;
        float qsc = (nt < 4) ? L2E : 1.0f;     // fold log2(e) into Q
        int coB = (nt & 3) * 128;
#pragma unroll
        for (int nn = 0; nn < 4; nn++)
#pragma unroll
            for (int m = 0; m < 4; m++)
#pragma unroll
                for (int r = 0; r < 4; r++)
                    Ts[(wm * 64 + m * 16 + lg * 4 + r) * 136 + wn * 64 + nn * 16 + ll]
                        = f2bf(acc[m][nn][r] * qsc);
        __syncthreads();
        int chunk = tid & 7;
#pragma unroll
        for (int j = 0; j < 8; j++) {
            int vr = j * 32 + (tid >> 3);
            int irow = vr >> 1, half = vr & 1;
            int hh = (coB >> 6) + half;
            u16* qdst = dst + ((size_t)(b * 8 + hh) * 1024 + nloc0 + irow) * 64;
            *(short8*)&qdst[chunk * 8] = *(const short8*)&Ts[irow * 136 + half * 64 + chunk * 8];
        }
    } else {
        // V tile: transpose via LDS -> Vt[bh][d][n]
#pragma unroll
        for (int nn = 0; nn < 4; nn++)
#pragma unroll
            for (int m = 0; m < 4; m++)
#pragma unroll
                for (int r = 0; r < 4; r++)
                    Ts[(wn * 64 + nn * 16 + ll) * 136 + wm * 64 + m * 16 + lg * 4 + r]
                        = f2bf(acc[m][nn][r]);
        __syncthreads();
        int co_l = tid >> 1, half = tid & 1;
        int co = (nt - 8) * 128 + co_l;
        int hh = (co >> 6) & 7, d = co & 63;
        u16* vdst = Vt + ((size_t)(b * 8 + hh) * 64 + d) * 1024 + nloc0 + half * 64;
#pragma unroll
        for (int j = 0; j < 8; j++)
            *(short8*)&vdst[j * 8] = *(const short8*)&Ts[co_l * 136 + half * 64 + j * 8];
    }
}

// ====== K2: flash attention, 32x32 MFMA, fused rel-logits (k1b absorbed) ========
// grid: 512 XCD-swizzled; block 256 (4 waves, 32 i-rows each)
__global__ __launch_bounds__(256, 2) void k2_attn(
    const u16* Q, const u16* K, const u16* Vt,
    const u16* relwb, const u16* relhb,
    const u16* WoT, const float* scaleZ, const float* shiftZ,
    u16* Z)
{
    int s_ = blockIdx.x;
    int xcd = s_ & 7, r8 = s_ >> 3;
    int it = r8 & 7, bh = (r8 >> 3) * 8 + xcd;    // 8 it-blocks of a bh share an XCD
    int b = bh >> 3, h = bh & 7;
    int tid = threadIdx.x;
    int wv = tid >> 6, l = tid & 63, il = l & 31, hf = l >> 5;
    int i0 = it * 128;
    int iw = i0 + wv * 32;

    __shared__ __align__(16) char smem[53760];
    u16*   Qs  = (u16*)smem;                 // [2][64][72] bf16
    u16*   Vs  = (u16*)(smem + 18432);       // [2][64][72] bf16
    float* rhS = (float*)(smem + 36864);     // [128][33] f32

    // K fragments: B[k=d][col=i], 4 k-slices of 16
    const u16* kb = K + ((size_t)bh * 1024 + iw) * 64;
    short8 kf0 = *(const short8*)&kb[il * 64 + hf * 8];
    short8 kf1 = *(const short8*)&kb[il * 64 + 16 + hf * 8];
    short8 kf2 = *(const short8*)&kb[il * 64 + 32 + hf * 8];
    short8 kf3 = *(const short8*)&kb[il * 64 + 48 + hf * 8];

    // ---- fused rel-logit prologue (replaces k1b kernel) ----
    float rw16[16];
    {
        float* wlb = (float*)(smem + wv * 8448);
        const u16* qsrc = Q + ((size_t)bh * 1024 + iw) * 64;
        short8 qa0 = *(const short8*)&qsrc[il * 64 + hf * 8];
        short8 qa1 = *(const short8*)&qsrc[il * 64 + 16 + hf * 8];
        short8 qa2 = *(const short8*)&qsrc[il * 64 + 32 + hf * 8];
        short8 qa3 = *(const short8*)&qsrc[il * 64 + 48 + hf * 8];
        int m1 = (32 + il > 62) ? 62 : 32 + il;   // col 63 never gathered
        const u16* rwsrc = relwb + h * 4032;
        const u16* rhsrc = relhb + h * 4032;
#pragma unroll
        for (int mt2 = 0; mt2 < 2; mt2++) {
            int m = mt2 ? m1 : il;
            short8 b0 = *(const short8*)&rwsrc[m * 64 + hf * 8];
            short8 b1 = *(const short8*)&rwsrc[m * 64 + 16 + hf * 8];
            short8 b2 = *(const short8*)&rwsrc[m * 64 + 32 + hf * 8];
            short8 b3 = *(const short8*)&rwsrc[m * 64 + 48 + hf * 8];
            f32x16 wa;
#pragma unroll
            for (int reg = 0; reg < 16; reg++) wa[reg] = 0.f;
            wa = MFMA32(qa0, b0, wa);
            wa = MFMA32(qa1, b1, wa);
            wa = MFMA32(qa2, b2, wa);
            wa = MFMA32(qa3, b3, wa);
#pragma unroll
            for (int reg = 0; reg < 16; reg++)
                wlb[((reg & 3) + 8 * (reg >> 2) + 4 * hf) * 66 + mt2 * 32 + il] = wa[reg];
        }
#pragma unroll
        for (int reg = 0; reg < 16; reg++) {
            int c = (reg & 3) + 8 * (reg >> 2) + 4 * hf;
            rw16[reg] = wlb[il * 65 + c + 31];      // il*66 + c + 31 - il
        }
#pragma unroll
        for (int mt2 = 0; mt2 < 2; mt2++) {
            int m = mt2 ? m1 : il;
            short8 b0 = *(const short8*)&rhsrc[m * 64 + hf * 8];
            short8 b1 = *(const short8*)&rhsrc[m * 64 + 16 + hf * 8];
            short8 b2 = *(const short8*)&rhsrc[m * 64 + 32 + hf * 8];
            short8 b3 = *(const short8*)&rhsrc[m * 64 + 48 + hf * 8];
            f32x16 ha;
#pragma unroll
            for (int reg = 0; reg < 16; reg++) ha[reg] = 0.f;
            ha = MFMA32(qa0, b0, ha);
            ha = MFMA32(qa1, b1, ha);
            ha = MFMA32(qa2, b2, ha);
            ha = MFMA32(qa3, b3, ha);
#pragma unroll
            for (int reg = 0; reg < 16; reg++)
                wlb[((reg & 3) + 8 * (reg >> 2) + 4 * hf) * 66 + mt2 * 32 + il] = ha[reg];
        }
        int x = iw >> 5;
#pragma unroll
        for (int reg = 0; reg < 16; reg++) {
            int c = (reg & 3) + 8 * (reg >> 2) + 4 * hf;
            rhS[(wv * 32 + il) * 33 + c] = wlb[il * 66 + c + 31 - x];
        }
    }
    __syncthreads();   // prologue scratch dead; staging area now safe

    f32x16 o0, o1;
#pragma unroll
    for (int reg = 0; reg < 16; reg++) { o0[reg] = 0.f; o1[reg] = 0.f; }
    float lsum = 0.f;

    const u16* qg = Q + (size_t)bh * 65536;
    const u16* vg = Vt + (size_t)bh * 65536;
    int srow = tid >> 2, sg = (tid & 3) * 8;   // 4 threads/row, granules sg, sg+32

    // prologue: chunk0 -> buf0; prefetch chunk1 into regs
    short8 pq0 = *(const short8*)&qg[(size_t)srow * 64 + sg];
    short8 pq1 = *(const short8*)&qg[(size_t)srow * 64 + sg + 32];
    short8 pv0 = *(const short8*)&vg[(size_t)srow * 1024 + sg];
    short8 pv1 = *(const short8*)&vg[(size_t)srow * 1024 + sg + 32];
    *(short8*)&Qs[srow * 72 + sg] = pq0;
    *(short8*)&Qs[srow * 72 + sg + 32] = pq1;
    *(short8*)&Vs[srow * 72 + sg] = pv0;
    *(short8*)&Vs[srow * 72 + sg + 32] = pv1;
    pq0 = *(const short8*)&qg[(size_t)(64 + srow) * 64 + sg];
    pq1 = *(const short8*)&qg[(size_t)(64 + srow) * 64 + sg + 32];
    pv0 = *(const short8*)&vg[(size_t)srow * 1024 + 64 + sg];
    pv1 = *(const short8*)&vg[(size_t)srow * 1024 + 64 + sg + 32];

    for (int ch = 0; ch < 16; ++ch) {
        int cur = ch & 1, nxt = cur ^ 1;
        barrier_lgkm();    // no vmcnt drain: keep ch+2 prefetch loads in flight
        if (ch < 15) {     // write chunk ch+1 into the other buffer
            *(short8*)&Qs[nxt * 4608 + srow * 72 + sg] = pq0;
            *(short8*)&Qs[nxt * 4608 + srow * 72 + sg + 32] = pq1;
            *(short8*)&Vs[nxt * 4608 + srow * 72 + sg] = pv0;
            *(short8*)&Vs[nxt * 4608 + srow * 72 + sg + 32] = pv1;
        }
        if (ch < 14) {     // issue chunk ch+2 loads
            int j2 = (ch + 2) * 64;
            pq0 = *(const short8*)&qg[(size_t)(j2 + srow) * 64 + sg];
            pq1 = *(const short8*)&qg[(size_t)(j2 + srow) * 64 + sg + 32];
            pv0 = *(const short8*)&vg[(size_t)srow * 1024 + j2 + sg];
            pv1 = *(const short8*)&vg[(size_t)srow * 1024 + j2 + sg + 32];
        }
        const u16* Qb = Qs + cur * 4608;
        const u16* Vb = Vs + cur * 4608;

#pragma unroll
        for (int u = 0; u < 2; ++u) {
            int jl = u * 32;
            float rhv = rhS[(wv * 32 + il) * 33 + ch * 2 + u];
            f32x16 sA;
#pragma unroll
            for (int reg = 0; reg < 16; reg++) sA[reg] = rw16[reg] + rhv;
            short8 aq0 = *(const short8*)&Qb[(jl + il) * 72 + hf * 8];
            short8 aq1 = *(const short8*)&Qb[(jl + il) * 72 + 16 + hf * 8];
            short8 aq2 = *(const short8*)&Qb[(jl + il) * 72 + 32 + hf * 8];
            short8 aq3 = *(const short8*)&Qb[(jl + il) * 72 + 48 + hf * 8];
            sA = MFMA32(aq0, kf0, sA);
            sA = MFMA32(aq1, kf1, sA);
            sA = MFMA32(aq2, kf2, sA);
            sA = MFMA32(aq3, kf3, sA);

            float p[16];
#pragma unroll
            for (int reg = 0; reg < 16; reg++) p[reg] = __builtin_amdgcn_exp2f(sA[reg]);
            {
                float t0 = (p[0] + p[1]) + (p[2] + p[3]);
                float t1 = (p[4] + p[5]) + (p[6] + p[7]);
                float t2 = (p[8] + p[9]) + (p[10] + p[11]);
                float t3 = (p[12] + p[13]) + (p[14] + p[15]);
                lsum += (t0 + t1) + (t2 + t3);
            }
            uint32_t W[8];
#pragma unroll
            for (int q = 0; q < 4; q++) {
                W[q * 2]     = cvtpk(p[q * 4 + 0], p[q * 4 + 1]);
                W[q * 2 + 1] = cvtpk(p[q * 4 + 2], p[q * 4 + 3]);
            }
            short8 pf0, pf1;
            {
                i32x2 rA = __builtin_amdgcn_permlane32_swap((int)W[0], (int)W[2], false, false);
                i32x2 rB = __builtin_amdgcn_permlane32_swap((int)W[1], (int)W[3], false, false);
                i32x4 t = { rA.x, rB.x, rA.y, rB.y };
                pf0 = *(short8*)&t;
            }
            {
                i32x2 rA = __builtin_amdgcn_permlane32_swap((int)W[4], (int)W[6], false, false);
                i32x2 rB = __builtin_amdgcn_permlane32_swap((int)W[5], (int)W[7], false, false);
                i32x4 t = { rA.x, rB.x, rA.y, rB.y };
                pf1 = *(short8*)&t;
            }

            __builtin_amdgcn_s_setprio(1);
            short8 av;
            av = *(const short8*)&Vb[il * 72 + jl + hf * 8];
            o0 = MFMA32(av, pf0, o0);
            av = *(const short8*)&Vb[(32 + il) * 72 + jl + hf * 8];
            o1 = MFMA32(av, pf0, o1);
            av = *(const short8*)&Vb[il * 72 + jl + 16 + hf * 8];
            o0 = MFMA32(av, pf1, o0);
            av = *(const short8*)&Vb[(32 + il) * 72 + jl + 16 + hf * 8];
            o1 = MFMA32(av, pf1, o1);
            __builtin_amdgcn_s_setprio(0);
        }
    }

    // total row-sum for col i=il: halves hf=0/1 cover disjoint j
    lsum += __shfl_xor(lsum, 32);
    float inv = 1.0f / lsum;
    __syncthreads();   // staging region reusable as per-wave O scratch

    u16* Ob = (u16*)smem + wv * 2304;      // [32][72] bf16, rows = i-local
#pragma unroll
    for (int q = 0; q < 4; q++) {
        uint32_t w0 = cvtpk(o0[q * 4 + 0] * inv, o0[q * 4 + 1] * inv);
        uint32_t w1 = cvtpk(o0[q * 4 + 2] * inv, o0[q * 4 + 3] * inv);
        *(uint32_t*)&Ob[il * 72 + q * 8 + hf * 4]     = w0;
        *(uint32_t*)&Ob[il * 72 + q * 8 + hf * 4 + 2] = w1;
        uint32_t w2 = cvtpk(o1[q * 4 + 0] * inv, o1[q * 4 + 1] * inv);
        uint32_t w3 = cvtpk(o1[q * 4 + 2] * inv, o1[q * 4 + 3] * inv);
        *(uint32_t*)&Ob[il * 72 + 32 + q * 8 + hf * 4]     = w2;
        *(uint32_t*)&Ob[il * 72 + 32 + q * 8 + hf * 4 + 2] = w3;
    }
    short8 ao0 = *(const short8*)&Ob[il * 72 + hf * 8];
    short8 ao1 = *(const short8*)&Ob[il * 72 + 16 + hf * 8];
    short8 ao2 = *(const short8*)&Ob[il * 72 + 32 + hf * 8];
    short8 ao3 = *(const short8*)&Ob[il * 72 + 48 + hf * 8];

    const u16* wob = WoT + h * 4096;
#pragma unroll
    for (int et = 0; et < 2; et++) {
        short8 bo0 = *(const short8*)&wob[(et * 32 + il) * 64 + hf * 8];
        short8 bo1 = *(const short8*)&wob[(et * 32 + il) * 64 + 16 + hf * 8];
        short8 bo2 = *(const short8*)&wob[(et * 32 + il) * 64 + 32 + hf * 8];
        short8 bo3 = *(const short8*)&wob[(et * 32 + il) * 64 + 48 + hf * 8];
        f32x16 zacc;
#pragma unroll
        for (int reg = 0; reg < 16; reg++) zacc[reg] = 0.f;
        zacc = MFMA32(ao0, bo0, zacc);
        zacc = MFMA32(ao1, bo1, zacc);
        zacc = MFMA32(ao2, bo2, zacc);
        zacc = MFMA32(ao3, bo3, zacc);
        int chn = h * 64 + et * 32 + il;
        float scv = scaleZ[chn], shv = shiftZ[chn];
#pragma unroll
        for (int reg = 0; reg < 16; reg++) {
            int i = iw + (reg & 3) + 8 * (reg >> 2) + 4 * hf;
            Z[((size_t)(b * 1024) + i) * 512 + chn] = f2bf(zacc[reg] * scv + shv);
        }
    }
}

// ================= K3: final 1x1 conv + residual (f32 out) =================
// grid: 1024, 64x64 tiles (XCD-swizzled). LDS-FREE: both operands stream from L2.
__global__ __launch_bounds__(256, 4) void k3_gemm(
    const u16* __restrict__ Zb, const u16* __restrict__ WoutT,
    const float* __restrict__ X, float* Y)
{
    int s = blockIdx.x;
    int xcd = s & 7, r8 = s >> 3;
    int nt = r8 & 7, mt = (r8 >> 3) * 8 + xcd;    // same-mt nt-blocks share an XCD
    int tid = threadIdx.x;
    int w = tid >> 6, l = tid & 63, lg = l >> 4, ll = l & 15;
    int wm = w >> 1, wn = w & 1;
    int i0 = mt * 64, co0 = nt * 64;

    const u16* Ag = Zb    + (size_t)(i0 + wm * 32 + ll) * 512 + lg * 8;
    const u16* Bg = WoutT + (size_t)(co0 + wn * 32 + ll) * 512 + lg * 8;

    f32x4 acc[2][2];
#pragma unroll
    for (int m = 0; m < 2; m++)
#pragma unroll
        for (int nn = 0; nn < 2; nn++) acc[m][nn] = (f32x4){0,0,0,0};

#pragma unroll
    for (int ks = 0; ks < 16; ++ks) {
        short8 af[2], bfr[2];
#pragma unroll
        for (int m = 0; m < 2; m++)
            af[m] = *(const short8*)&Ag[m * 16 * 512 + ks * 32];
#pragma unroll
        for (int nn = 0; nn < 2; nn++)
            bfr[nn] = *(const short8*)&Bg[nn * 16 * 512 + ks * 32];
#pragma unroll
        for (int m = 0; m < 2; m++)
#pragma unroll
            for (int nn = 0; nn < 2; nn++)
                acc[m][nn] = MFMA(af[m], bfr[nn], acc[m][nn]);
    }

#pragma unroll
    for (int m = 0; m < 2; m++)
#pragma unroll
        for (int nn = 0; nn < 2; nn++) {
            int i = i0 + wm * 32 + m * 16 + lg * 4;
            int co = co0 + wn * 32 + nn * 16 + ll;
#pragma unroll
            for (int r = 0; r < 4; r++) {
                size_t idx = (size_t)(i + r) * 512 + co;
                Y[idx] = acc[m][nn][r] + X[idx];
            }
        }
}

// ================= launch =================
extern "C" void kernel_launch(void* const* d_in, const int* in_sizes, int n_in,
                              void* d_out, int out_size, void* d_ws, size_t ws_size,
                              hipStream_t stream)
{
    const float* x     = (const float*)d_in[0];
    const float* Wk    = (const float*)d_in[1];
    const float* Wq    = (const float*)d_in[2];
    const float* Wv    = (const float*)d_in[3];
    const float* Wo    = (const float*)d_in[4];
    const float* gamma = (const float*)d_in[5];
    const float* beta  = (const float*)d_in[6];
    const float* mmean = (const float*)d_in[7];
    const float* mvar  = (const float*)d_in[8];
    const float* relw  = (const float*)d_in[9];
    const float* relh  = (const float*)d_in[10];
    const float* Wout  = (const float*)d_in[11];

    char* ws = (char*)d_ws;
    u16*   W1T    = (u16*)(ws + WS_W1T);
    u16*   WoT    = (u16*)(ws + WS_WOT);
    u16*   WoutT  = (u16*)(ws + WS_WOUTT);
    u16*   RWbf   = (u16*)(ws + WS_RELW);
    u16*   RHbf   = (u16*)(ws + WS_RELH);
    float* scaleZ = (float*)(ws + WS_SCALE);
    float* shiftZ = (float*)(ws + WS_SHIFT);
    u16*   Qw     = (u16*)(ws + WS_Q);
    u16*   Kw     = (u16*)(ws + WS_K);
    u16*   Vtw    = (u16*)(ws + WS_VT);
    u16*   Zw     = (u16*)(ws + WS_Z);

    k0_setup<<<4478, 256, 0, stream>>>(Wk, Wq, Wv, Wo, gamma, beta, mmean, mvar,
                                       relw, relh, Wout,
                                       W1T, WoT, WoutT, RWbf, RHbf,
                                       scaleZ, shiftZ);
    k1_gemm<<<768, 256, 0, stream>>>(x, W1T, Qw, Kw, Vtw);
    k2_attn<<<512, 256, 0, stream>>>(Qw, Kw, Vtw, RWbf, RHbf, WoT, scaleZ, shiftZ, Zw);
    k3_gemm<<<1024, 256, 0, stream>>>(Zw, WoutT, x, (float*)d_out);
}

// Round 12
// 103.595 us; speedup vs baseline: 1.0803x; 1.0803x over previous
//
#include <hip/hip_runtime.h>
#include <stdint.h>

typedef unsigned short u16;
typedef __attribute__((ext_vector_type(8))) short short8;   // 8 x bf16 fragment
typedef __attribute__((ext_vector_type(4))) float f32x4;
typedef __attribute__((ext_vector_type(16))) float f32x16;
typedef __attribute__((ext_vector_type(4))) unsigned short us4;
typedef __attribute__((ext_vector_type(4))) uint32_t u32x4;
typedef __attribute__((ext_vector_type(2))) int i32x2;
typedef __attribute__((ext_vector_type(4))) int i32x4;

#define MFMA(a,b,c)   __builtin_amdgcn_mfma_f32_16x16x32_bf16((a),(b),(c),0,0,0)
#define MFMA32(a,b,c) __builtin_amdgcn_mfma_f32_32x32x16_bf16((a),(b),(c),0,0,0)
#define L2E 1.44269504f

__device__ __forceinline__ u16 f2bf(float f){
    union { float f; uint32_t i; } v; v.f = f;
    uint32_t u = v.i;
    return (u16)((u + 0x7fffu + ((u >> 16) & 1u)) >> 16);
}
__device__ __forceinline__ uint32_t cvtpk(float lo, float hi){
    uint32_t r;
    asm("v_cvt_pk_bf16_f32 %0, %1, %2" : "=v"(r) : "v"(lo), "v"(hi));
    return r;
}
// barrier without the vmcnt(0) drain __syncthreads would emit
__device__ __forceinline__ void barrier_lgkm(){
    __builtin_amdgcn_sched_barrier(0);
    asm volatile("s_waitcnt lgkmcnt(0)" ::: "memory");
    __builtin_amdgcn_s_barrier();
    __builtin_amdgcn_sched_barrier(0);
}

// ---------------- workspace layout (bytes) ----------------
#define WS_W1T    0u           // [1536][512] bf16  rows: [Wq h0..7 | Wk | Wv] x d
#define WS_WOT    1572864u     // [8][64][64] bf16  (WoT[h][e'][e])
#define WS_WOUTT  1638400u     // [512][512] bf16   (WoutT[co][c])
#define WS_RELW   2162688u     // [8][63][64] bf16
#define WS_RELH   2227200u
#define WS_SCALE  2291712u     // [512] f32
#define WS_SHIFT  2293760u     // [512] f32
#define WS_Q      10684416u    // [64][1024][64] bf16 (pre-scaled by log2(e))
#define WS_K      19073024u
#define WS_VT     27461632u    // [64][64][1024] bf16 (Vt[bh][d][n])
#define WS_Z      52627456u    // [8192][512] bf16

// ================= K0: weight transposes + BN fold =================
__global__ __launch_bounds__(256) void k0_setup(
    const float* Wk, const float* Wq, const float* Wv, const float* Wo,
    const float* gamma, const float* beta, const float* mean, const float* var,
    const float* relw, const float* relh, const float* Wout,
    u16* W1T, u16* WoT, u16* WoutT,
    u16* RWbf, u16* RHbf, float* scaleZ, float* shiftZ)
{
    int idx = blockIdx.x * 256 + threadIdx.x;
    if (idx < 786432) {
        int co = idx >> 9, c = idx & 511;
        int p = co >> 9, rem = co & 511;
        int h = rem >> 6, d = rem & 63;
        const float* src = (p == 0) ? Wq : (p == 1) ? Wk : Wv;
        W1T[idx] = f2bf(src[h * 32768 + c * 64 + d]);
    } else if (idx < 819200) {
        int r = idx - 786432;
        int h = r >> 12; int e = (r & 4095) >> 6, ep = r & 63;
        WoT[h * 4096 + ep * 64 + e] = f2bf(Wo[h * 4096 + e * 64 + ep]);
    } else if (idx < 1081344) {
        int r = idx - 819200;
        int c = r >> 9, co = r & 511;
        WoutT[co * 512 + c] = f2bf(Wout[c * 512 + co]);
    } else if (idx < 1145856) {
        int r = idx - 1081344;
        if (r < 32256) RWbf[r] = f2bf(relw[r]);
        else           RHbf[r - 32256] = f2bf(relh[r - 32256]);
    } else if (idx < 1146368) {
        int ch = idx - 1145856;
        float sc = gamma[ch] * rsqrtf(var[ch] + 1e-3f);
        scaleZ[ch] = sc;
        shiftZ[ch] = beta[ch] - mean[ch] * sc;
    }
}

__device__ __forceinline__ void packA(u16* dst, f32x4 a0, f32x4 a1, f32x4 a2, f32x4 a3){
    u32x4 v0 = { cvtpk(a0.x,a0.y), cvtpk(a0.z,a0.w), cvtpk(a1.x,a1.y), cvtpk(a1.z,a1.w) };
    u32x4 v1 = { cvtpk(a2.x,a2.y), cvtpk(a2.z,a2.w), cvtpk(a3.x,a3.y), cvtpk(a3.z,a3.w) };
    *(u32x4*)dst = v0;
    *(u32x4*)(dst + 8) = v1;
}

// ================= K1: fused QKV projection GEMM (reads f32 x directly) =========
// grid: 768 (XCD-swizzled); nt: 0-3 Q, 4-7 K, 8-11 V; Q scaled by log2(e)
// ROUND-10 PROVEN VERSION: A and B both staged via double-buffered LDS.
__global__ __launch_bounds__(256, 3) void k1_gemm(
    const float* __restrict__ Xf, const u16* __restrict__ W1T,
    u16* Q, u16* K, u16* Vt)
{
    int s = blockIdx.x;
    int xcd = s & 7, r8 = s >> 3;
    int nt = r8 % 12, mt = (r8 / 12) * 8 + xcd;   // same-mt blocks share an XCD
    int tid = threadIdx.x;
    int w = tid >> 6, l = tid & 63, lg = l >> 4, ll = l & 15;
    int wm = w >> 1, wn = w & 1;
    int i0 = mt * 128, co0 = nt * 128;

    __shared__ __align__(16) u16 SM[20480];   // As[2][5120] | Bs[2][5120]
    u16* As = SM;
    u16* Bs = SM + 10240;

    int row = tid >> 1, c16 = (tid & 1) * 16;
    int st = row * 40 + c16;
    const float* ArowF = Xf + (size_t)(i0 + row) * 512 + c16;
    const u16*   Brow  = W1T + (size_t)(co0 + row) * 512 + c16;

    f32x4 acc[4][4];
#pragma unroll
    for (int m = 0; m < 4; m++)
#pragma unroll
        for (int nn = 0; nn < 4; nn++) acc[m][nn] = (f32x4){0,0,0,0};

    f32x4 ra0 = *(const f32x4*)&ArowF[0];
    f32x4 ra1 = *(const f32x4*)&ArowF[4];
    f32x4 ra2 = *(const f32x4*)&ArowF[8];
    f32x4 ra3 = *(const f32x4*)&ArowF[12];
    short8 rb0 = *(const short8*)&Brow[0];
    short8 rb1 = *(const short8*)&Brow[8];
    packA(&As[st], ra0, ra1, ra2, ra3);
    *(short8*)&Bs[st] = rb0; *(short8*)&Bs[st + 8] = rb1;
    __syncthreads();
    for (int ks = 0; ks < 16; ++ks) {
        int cur = ks & 1, nxt = cur ^ 1;
        if (ks < 15) {
            ra0 = *(const f32x4*)&ArowF[(ks + 1) * 32];
            ra1 = *(const f32x4*)&ArowF[(ks + 1) * 32 + 4];
            ra2 = *(const f32x4*)&ArowF[(ks + 1) * 32 + 8];
            ra3 = *(const f32x4*)&ArowF[(ks + 1) * 32 + 12];
            rb0 = *(const short8*)&Brow[(ks + 1) * 32];
            rb1 = *(const short8*)&Brow[(ks + 1) * 32 + 8];
        }
        const u16* Ab = As + cur * 5120;
        const u16* Bb = Bs + cur * 5120;
        short8 af[4], bfr[4];
#pragma unroll
        for (int m = 0; m < 4; m++)
            af[m] = *(const short8*)&Ab[(wm * 64 + m * 16 + ll) * 40 + lg * 8];
#pragma unroll
        for (int nn = 0; nn < 4; nn++)
            bfr[nn] = *(const short8*)&Bb[(wn * 64 + nn * 16 + ll) * 40 + lg * 8];
#pragma unroll
        for (int m = 0; m < 4; m++)
#pragma unroll
            for (int nn = 0; nn < 4; nn++)
                acc[m][nn] = MFMA(af[m], bfr[nn], acc[m][nn]);
        if (ks < 15) {
            int so = nxt * 5120 + st;
            packA(&As[so], ra0, ra1, ra2, ra3);
            *(short8*)&Bs[so] = rb0; *(short8*)&Bs[so + 8] = rb1;
        }
        __syncthreads();
    }

    int b = mt >> 3, nloc0 = (mt & 7) * 128;
    u16* Ts = SM;                        // [128][136] u16 = 34.8 KB
    if (nt < 8) {
        u16* dst = (nt < 4) ? Q : K;
        float qsc = (nt < 4) ? L2E : 1.0f;     // fold log2(e) into Q
        int coB = (nt & 3) * 128;
#pragma unroll
        for (int nn = 0; nn < 4; nn++)
#pragma unroll
            for (int m = 0; m < 4; m++)
#pragma unroll
                for (int r = 0; r < 4; r++)
                    Ts[(wm * 64 + m * 16 + lg * 4 + r) * 136 + wn * 64 + nn * 16 + ll]
                        = f2bf(acc[m][nn][r] * qsc);
        __syncthreads();
        int chunk = tid & 7;
#pragma unroll
        for (int j = 0; j < 8; j++) {
            int vr = j * 32 + (tid >> 3);
            int irow = vr >> 1, half = vr & 1;
            int hh = (coB >> 6) + half;
            u16* qdst = dst + ((size_t)(b * 8 + hh) * 1024 + nloc0 + irow) * 64;
            *(short8*)&qdst[chunk * 8] = *(const short8*)&Ts[irow * 136 + half * 64 + chunk * 8];
        }
    } else {
        // V tile: transpose via LDS -> Vt[bh][d][n]
#pragma unroll
        for (int nn = 0; nn < 4; nn++)
#pragma unroll
            for (int m = 0; m < 4; m++)
#pragma unroll
                for (int r = 0; r < 4; r++)
                    Ts[(wn * 64 + nn * 16 + ll) * 136 + wm * 64 + m * 16 + lg * 4 + r]
                        = f2bf(acc[m][nn][r]);
        __syncthreads();
        int co_l = tid >> 1, half = tid & 1;
        int co = (nt - 8) * 128 + co_l;
        int hh = (co >> 6) & 7, d = co & 63;
        u16* vdst = Vt + ((size_t)(b * 8 + hh) * 64 + d) * 1024 + nloc0 + half * 64;
#pragma unroll
        for (int j = 0; j < 8; j++)
            *(short8*)&vdst[j * 8] = *(const short8*)&Ts[co_l * 136 + half * 64 + j * 8];
    }
}

// ====== K2: flash attention, 32x32 MFMA, fused rel-logits (k1b absorbed) ========
// grid: 512 XCD-swizzled; block 256 (4 waves, 32 i-rows each)
__global__ __launch_bounds__(256, 2) void k2_attn(
    const u16* Q, const u16* K, const u16* Vt,
    const u16* relwb, const u16* relhb,
    const u16* WoT, const float* scaleZ, const float* shiftZ,
    u16* Z)
{
    int s_ = blockIdx.x;
    int xcd = s_ & 7, r8 = s_ >> 3;
    int it = r8 & 7, bh = (r8 >> 3) * 8 + xcd;    // 8 it-blocks of a bh share an XCD
    int b = bh >> 3, h = bh & 7;
    int tid = threadIdx.x;
    int wv = tid >> 6, l = tid & 63, il = l & 31, hf = l >> 5;
    int i0 = it * 128;
    int iw = i0 + wv * 32;

    __shared__ __align__(16) char smem[53760];
    u16*   Qs  = (u16*)smem;                 // [2][64][72] bf16
    u16*   Vs  = (u16*)(smem + 18432);       // [2][64][72] bf16
    float* rhS = (float*)(smem + 36864);     // [128][33] f32

    // K fragments: B[k=d][col=i], 4 k-slices of 16
    const u16* kb = K + ((size_t)bh * 1024 + iw) * 64;
    short8 kf0 = *(const short8*)&kb[il * 64 + hf * 8];
    short8 kf1 = *(const short8*)&kb[il * 64 + 16 + hf * 8];
    short8 kf2 = *(const short8*)&kb[il * 64 + 32 + hf * 8];
    short8 kf3 = *(const short8*)&kb[il * 64 + 48 + hf * 8];

    // ---- fused rel-logit prologue (replaces k1b kernel) ----
    float rw16[16];
    {
        float* wlb = (float*)(smem + wv * 8448);
        const u16* qsrc = Q + ((size_t)bh * 1024 + iw) * 64;
        short8 qa0 = *(const short8*)&qsrc[il * 64 + hf * 8];
        short8 qa1 = *(const short8*)&qsrc[il * 64 + 16 + hf * 8];
        short8 qa2 = *(const short8*)&qsrc[il * 64 + 32 + hf * 8];
        short8 qa3 = *(const short8*)&qsrc[il * 64 + 48 + hf * 8];
        int m1 = (32 + il > 62) ? 62 : 32 + il;   // col 63 never gathered
        const u16* rwsrc = relwb + h * 4032;
        const u16* rhsrc = relhb + h * 4032;
#pragma unroll
        for (int mt2 = 0; mt2 < 2; mt2++) {
            int m = mt2 ? m1 : il;
            short8 b0 = *(const short8*)&rwsrc[m * 64 + hf * 8];
            short8 b1 = *(const short8*)&rwsrc[m * 64 + 16 + hf * 8];
            short8 b2 = *(const short8*)&rwsrc[m * 64 + 32 + hf * 8];
            short8 b3 = *(const short8*)&rwsrc[m * 64 + 48 + hf * 8];
            f32x16 wa;
#pragma unroll
            for (int reg = 0; reg < 16; reg++) wa[reg] = 0.f;
            wa = MFMA32(qa0, b0, wa);
            wa = MFMA32(qa1, b1, wa);
            wa = MFMA32(qa2, b2, wa);
            wa = MFMA32(qa3, b3, wa);
#pragma unroll
            for (int reg = 0; reg < 16; reg++)
                wlb[((reg & 3) + 8 * (reg >> 2) + 4 * hf) * 66 + mt2 * 32 + il] = wa[reg];
        }
#pragma unroll
        for (int reg = 0; reg < 16; reg++) {
            int c = (reg & 3) + 8 * (reg >> 2) + 4 * hf;
            rw16[reg] = wlb[il * 65 + c + 31];      // il*66 + c + 31 - il
        }
#pragma unroll
        for (int mt2 = 0; mt2 < 2; mt2++) {
            int m = mt2 ? m1 : il;
            short8 b0 = *(const short8*)&rhsrc[m * 64 + hf * 8];
            short8 b1 = *(const short8*)&rhsrc[m * 64 + 16 + hf * 8];
            short8 b2 = *(const short8*)&rhsrc[m * 64 + 32 + hf * 8];
            short8 b3 = *(const short8*)&rhsrc[m * 64 + 48 + hf * 8];
            f32x16 ha;
#pragma unroll
            for (int reg = 0; reg < 16; reg++) ha[reg] = 0.f;
            ha = MFMA32(qa0, b0, ha);
            ha = MFMA32(qa1, b1, ha);
            ha = MFMA32(qa2, b2, ha);
            ha = MFMA32(qa3, b3, ha);
#pragma unroll
            for (int reg = 0; reg < 16; reg++)
                wlb[((reg & 3) + 8 * (reg >> 2) + 4 * hf) * 66 + mt2 * 32 + il] = ha[reg];
        }
        int x = iw >> 5;
#pragma unroll
        for (int reg = 0; reg < 16; reg++) {
            int c = (reg & 3) + 8 * (reg >> 2) + 4 * hf;
            rhS[(wv * 32 + il) * 33 + c] = wlb[il * 66 + c + 31 - x];
        }
    }
    __syncthreads();   // prologue scratch dead; staging area now safe

    f32x16 o0, o1;
#pragma unroll
    for (int reg = 0; reg < 16; reg++) { o0[reg] = 0.f; o1[reg] = 0.f; }
    float lsum = 0.f;

    const u16* qg = Q + (size_t)bh * 65536;
    const u16* vg = Vt + (size_t)bh * 65536;
    int srow = tid >> 2, sg = (tid & 3) * 8;   // 4 threads/row, granules sg, sg+32

    // prologue: chunk0 -> buf0; prefetch chunk1 into regs
    short8 pq0 = *(const short8*)&qg[(size_t)srow * 64 + sg];
    short8 pq1 = *(const short8*)&qg[(size_t)srow * 64 + sg + 32];
    short8 pv0 = *(const short8*)&vg[(size_t)srow * 1024 + sg];
    short8 pv1 = *(const short8*)&vg[(size_t)srow * 1024 + sg + 32];
    *(short8*)&Qs[srow * 72 + sg] = pq0;
    *(short8*)&Qs[srow * 72 + sg + 32] = pq1;
    *(short8*)&Vs[srow * 72 + sg] = pv0;
    *(short8*)&Vs[srow * 72 + sg + 32] = pv1;
    pq0 = *(const short8*)&qg[(size_t)(64 + srow) * 64 + sg];
    pq1 = *(const short8*)&qg[(size_t)(64 + srow) * 64 + sg + 32];
    pv0 = *(const short8*)&vg[(size_t)srow * 1024 + 64 + sg];
    pv1 = *(const short8*)&vg[(size_t)srow * 1024 + 64 + sg + 32];

    for (int ch = 0; ch < 16; ++ch) {
        int cur = ch & 1, nxt = cur ^ 1;
        barrier_lgkm();    // no vmcnt drain: keep ch+2 prefetch loads in flight
        if (ch < 15) {     // write chunk ch+1 into the other buffer
            *(short8*)&Qs[nxt * 4608 + srow * 72 + sg] = pq0;
            *(short8*)&Qs[nxt * 4608 + srow * 72 + sg + 32] = pq1;
            *(short8*)&Vs[nxt * 4608 + srow * 72 + sg] = pv0;
            *(short8*)&Vs[nxt * 4608 + srow * 72 + sg + 32] = pv1;
        }
        if (ch < 14) {     // issue chunk ch+2 loads
            int j2 = (ch + 2) * 64;
            pq0 = *(const short8*)&qg[(size_t)(j2 + srow) * 64 + sg];
            pq1 = *(const short8*)&qg[(size_t)(j2 + srow) * 64 + sg + 32];
            pv0 = *(const short8*)&vg[(size_t)srow * 1024 + j2 + sg];
            pv1 = *(const short8*)&vg[(size_t)srow * 1024 + j2 + sg + 32];
        }
        const u16* Qb = Qs + cur * 4608;
        const u16* Vb = Vs + cur * 4608;

#pragma unroll
        for (int u = 0; u < 2; ++u) {
            int jl = u * 32;
            float rhv = rhS[(wv * 32 + il) * 33 + ch * 2 + u];
            f32x16 sA;
#pragma unroll
            for (int reg = 0; reg < 16; reg++) sA[reg] = rw16[reg] + rhv;
            short8 aq0 = *(const short8*)&Qb[(jl + il) * 72 + hf * 8];
            short8 aq1 = *(const short8*)&Qb[(jl + il) * 72 + 16 + hf * 8];
            short8 aq2 = *(const short8*)&Qb[(jl + il) * 72 + 32 + hf * 8];
            short8 aq3 = *(const short8*)&Qb[(jl + il) * 72 + 48 + hf * 8];
            sA = MFMA32(aq0, kf0, sA);
            sA = MFMA32(aq1, kf1, sA);
            sA = MFMA32(aq2, kf2, sA);
            sA = MFMA32(aq3, kf3, sA);

            float p[16];
#pragma unroll
            for (int reg = 0; reg < 16; reg++) p[reg] = __builtin_amdgcn_exp2f(sA[reg]);
            {
                float t0 = (p[0] + p[1]) + (p[2] + p[3]);
                float t1 = (p[4] + p[5]) + (p[6] + p[7]);
                float t2 = (p[8] + p[9]) + (p[10] + p[11]);
                float t3 = (p[12] + p[13]) + (p[14] + p[15]);
                lsum += (t0 + t1) + (t2 + t3);
            }
            uint32_t W[8];
#pragma unroll
            for (int q = 0; q < 4; q++) {
                W[q * 2]     = cvtpk(p[q * 4 + 0], p[q * 4 + 1]);
                W[q * 2 + 1] = cvtpk(p[q * 4 + 2], p[q * 4 + 3]);
            }
            short8 pf0, pf1;
            {
                i32x2 rA = __builtin_amdgcn_permlane32_swap((int)W[0], (int)W[2], false, false);
                i32x2 rB = __builtin_amdgcn_permlane32_swap((int)W[1], (int)W[3], false, false);
                i32x4 t = { rA.x, rB.x, rA.y, rB.y };
                pf0 = *(short8*)&t;
            }
            {
                i32x2 rA = __builtin_amdgcn_permlane32_swap((int)W[4], (int)W[6], false, false);
                i32x2 rB = __builtin_amdgcn_permlane32_swap((int)W[5], (int)W[7], false, false);
                i32x4 t = { rA.x, rB.x, rA.y, rB.y };
                pf1 = *(short8*)&t;
            }

            __builtin_amdgcn_s_setprio(1);
            short8 av;
            av = *(const short8*)&Vb[il * 72 + jl + hf * 8];
            o0 = MFMA32(av, pf0, o0);
            av = *(const short8*)&Vb[(32 + il) * 72 + jl + hf * 8];
            o1 = MFMA32(av, pf0, o1);
            av = *(const short8*)&Vb[il * 72 + jl + 16 + hf * 8];
            o0 = MFMA32(av, pf1, o0);
            av = *(const short8*)&Vb[(32 + il) * 72 + jl + 16 + hf * 8];
            o1 = MFMA32(av, pf1, o1);
            __builtin_amdgcn_s_setprio(0);
        }
    }

    // total row-sum for col i=il: halves hf=0/1 cover disjoint j
    lsum += __shfl_xor(lsum, 32);
    float inv = 1.0f / lsum;
    __syncthreads();   // staging region reusable as per-wave O scratch

    u16* Ob = (u16*)smem + wv * 2304;      // [32][72] bf16, rows = i-local
#pragma unroll
    for (int q = 0; q < 4; q++) {
        uint32_t w0 = cvtpk(o0[q * 4 + 0] * inv, o0[q * 4 + 1] * inv);
        uint32_t w1 = cvtpk(o0[q * 4 + 2] * inv, o0[q * 4 + 3] * inv);
        *(uint32_t*)&Ob[il * 72 + q * 8 + hf * 4]     = w0;
        *(uint32_t*)&Ob[il * 72 + q * 8 + hf * 4 + 2] = w1;
        uint32_t w2 = cvtpk(o1[q * 4 + 0] * inv, o1[q * 4 + 1] * inv);
        uint32_t w3 = cvtpk(o1[q * 4 + 2] * inv, o1[q * 4 + 3] * inv);
        *(uint32_t*)&Ob[il * 72 + 32 + q * 8 + hf * 4]     = w2;
        *(uint32_t*)&Ob[il * 72 + 32 + q * 8 + hf * 4 + 2] = w3;
    }
    short8 ao0 = *(const short8*)&Ob[il * 72 + hf * 8];
    short8 ao1 = *(const short8*)&Ob[il * 72 + 16 + hf * 8];
    short8 ao2 = *(const short8*)&Ob[il * 72 + 32 + hf * 8];
    short8 ao3 = *(const short8*)&Ob[il * 72 + 48 + hf * 8];

    const u16* wob = WoT + h * 4096;
#pragma unroll
    for (int et = 0; et < 2; et++) {
        short8 bo0 = *(const short8*)&wob[(et * 32 + il) * 64 + hf * 8];
        short8 bo1 = *(const short8*)&wob[(et * 32 + il) * 64 + 16 + hf * 8];
        short8 bo2 = *(const short8*)&wob[(et * 32 + il) * 64 + 32 + hf * 8];
        short8 bo3 = *(const short8*)&wob[(et * 32 + il) * 64 + 48 + hf * 8];
        f32x16 zacc;
#pragma unroll
        for (int reg = 0; reg < 16; reg++) zacc[reg] = 0.f;
        zacc = MFMA32(ao0, bo0, zacc);
        zacc = MFMA32(ao1, bo1, zacc);
        zacc = MFMA32(ao2, bo2, zacc);
        zacc = MFMA32(ao3, bo3, zacc);
        int chn = h * 64 + et * 32 + il;
        float scv = scaleZ[chn], shv = shiftZ[chn];
#pragma unroll
        for (int reg = 0; reg < 16; reg++) {
            int i = iw + (reg & 3) + 8 * (reg >> 2) + 4 * hf;
            Z[((size_t)(b * 1024) + i) * 512 + chn] = f2bf(zacc[reg] * scv + shv);
        }
    }
}

// ================= K3: final 1x1 conv + residual (f32 out) =================
// grid: 1024, 64x64 tiles (XCD-swizzled). LDS-FREE: both operands stream from L2
// (no barriers -> compiler software-pipelines the loads freely).
__global__ __launch_bounds__(256, 4) void k3_gemm(
    const u16* __restrict__ Zb, const u16* __restrict__ WoutT,
    const float* __restrict__ X, float* Y)
{
    int s = blockIdx.x;
    int xcd = s & 7, r8 = s >> 3;
    int nt = r8 & 7, mt = (r8 >> 3) * 8 + xcd;    // same-mt nt-blocks share an XCD
    int tid = threadIdx.x;
    int w = tid >> 6, l = tid & 63, lg = l >> 4, ll = l & 15;
    int wm = w >> 1, wn = w & 1;
    int i0 = mt * 64, co0 = nt * 64;

    const u16* Ag = Zb    + (size_t)(i0 + wm * 32 + ll) * 512 + lg * 8;
    const u16* Bg = WoutT + (size_t)(co0 + wn * 32 + ll) * 512 + lg * 8;

    f32x4 acc[2][2];
#pragma unroll
    for (int m = 0; m < 2; m++)
#pragma unroll
        for (int nn = 0; nn < 2; nn++) acc[m][nn] = (f32x4){0,0,0,0};

#pragma unroll
    for (int ks = 0; ks < 16; ++ks) {
        short8 af[2], bfr[2];
#pragma unroll
        for (int m = 0; m < 2; m++)
            af[m] = *(const short8*)&Ag[m * 16 * 512 + ks * 32];
#pragma unroll
        for (int nn = 0; nn < 2; nn++)
            bfr[nn] = *(const short8*)&Bg[nn * 16 * 512 + ks * 32];
#pragma unroll
        for (int m = 0; m < 2; m++)
#pragma unroll
            for (int nn = 0; nn < 2; nn++)
                acc[m][nn] = MFMA(af[m], bfr[nn], acc[m][nn]);
    }

#pragma unroll
    for (int m = 0; m < 2; m++)
#pragma unroll
        for (int nn = 0; nn < 2; nn++) {
            int i = i0 + wm * 32 + m * 16 + lg * 4;
            int co = co0 + wn * 32 + nn * 16 + ll;
#pragma unroll
            for (int r = 0; r < 4; r++) {
                size_t idx = (size_t)(i + r) * 512 + co;
                Y[idx] = acc[m][nn][r] + X[idx];
            }
        }
}

// ================= launch =================
extern "C" void kernel_launch(void* const* d_in, const int* in_sizes, int n_in,
                              void* d_out, int out_size, void* d_ws, size_t ws_size,
                              hipStream_t stream)
{
    const float* x     = (const float*)d_in[0];
    const float* Wk    = (const float*)d_in[1];
    const float* Wq    = (const float*)d_in[2];
    const float* Wv    = (const float*)d_in[3];
    const float* Wo    = (const float*)d_in[4];
    const float* gamma = (const float*)d_in[5];
    const float* beta  = (const float*)d_in[6];
    const float* mmean = (const float*)d_in[7];
    const float* mvar  = (const float*)d_in[8];
    const float* relw  = (const float*)d_in[9];
    const float* relh  = (const float*)d_in[10];
    const float* Wout  = (const float*)d_in[11];

    char* ws = (char*)d_ws;
    u16*   W1T    = (u16*)(ws + WS_W1T);
    u16*   WoT    = (u16*)(ws + WS_WOT);
    u16*   WoutT  = (u16*)(ws + WS_WOUTT);
    u16*   RWbf   = (u16*)(ws + WS_RELW);
    u16*   RHbf   = (u16*)(ws + WS_RELH);
    float* scaleZ = (float*)(ws + WS_SCALE);
    float* shiftZ = (float*)(ws + WS_SHIFT);
    u16*   Qw     = (u16*)(ws + WS_Q);
    u16*   Kw     = (u16*)(ws + WS_K);
    u16*   Vtw    = (u16*)(ws + WS_VT);
    u16*   Zw     = (u16*)(ws + WS_Z);

    k0_setup<<<4478, 256, 0, stream>>>(Wk, Wq, Wv, Wo, gamma, beta, mmean, mvar,
                                       relw, relh, Wout,
                                       W1T, WoT, WoutT, RWbf, RHbf,
                                       scaleZ, shiftZ);
    k1_gemm<<<768, 256, 0, stream>>>(x, W1T, Qw, Kw, Vtw);
    k2_attn<<<512, 256, 0, stream>>>(Qw, Kw, Vtw, RWbf, RHbf, WoT, scaleZ, shiftZ, Zw);
    k3_gemm<<<1024, 256, 0, stream>>>(Zw, WoutT, x, (float*)d_out);
}

// Round 13
// 85.398 us; speedup vs baseline: 1.3105x; 1.2131x over previous
//
#include <hip/hip_runtime.h>
#include <stdint.h>

typedef unsigned short u16;
typedef __attribute__((ext_vector_type(8))) short short8;   // 8 x bf16 fragment
typedef __attribute__((ext_vector_type(4))) float f32x4;
typedef __attribute__((ext_vector_type(16))) float f32x16;
typedef __attribute__((ext_vector_type(4))) unsigned short us4;
typedef __attribute__((ext_vector_type(4))) uint32_t u32x4;
typedef __attribute__((ext_vector_type(2))) int i32x2;
typedef __attribute__((ext_vector_type(4))) int i32x4;

#define MFMA(a,b,c)   __builtin_amdgcn_mfma_f32_16x16x32_bf16((a),(b),(c),0,0,0)
#define MFMA32(a,b,c) __builtin_amdgcn_mfma_f32_32x32x16_bf16((a),(b),(c),0,0,0)
#define L2E 1.44269504f

__device__ __forceinline__ u16 f2bf(float f){
    union { float f; uint32_t i; } v; v.f = f;
    uint32_t u = v.i;
    return (u16)((u + 0x7fffu + ((u >> 16) & 1u)) >> 16);
}
__device__ __forceinline__ uint32_t cvtpk(float lo, float hi){
    uint32_t r;
    asm("v_cvt_pk_bf16_f32 %0, %1, %2" : "=v"(r) : "v"(lo), "v"(hi));
    return r;
}
// barrier without the vmcnt(0) drain __syncthreads would emit
__device__ __forceinline__ void barrier_lgkm(){
    __builtin_amdgcn_sched_barrier(0);
    asm volatile("s_waitcnt lgkmcnt(0)" ::: "memory");
    __builtin_amdgcn_s_barrier();
    __builtin_amdgcn_sched_barrier(0);
}

// ---------------- workspace layout (bytes) ----------------
#define WS_W1T    0u           // [1536][512] bf16  rows: [Wq h0..7 | Wk | Wv] x d
#define WS_WOT    1572864u     // [8][64][64] bf16  (WoT[h][e'][e])
#define WS_WOUTT  1638400u     // [512][512] bf16   (WoutT[co][c])
#define WS_RELW   2162688u     // [8][63][64] bf16
#define WS_RELH   2227200u
#define WS_SCALE  2291712u     // [512] f32
#define WS_SHIFT  2293760u     // [512] f32
#define WS_Q      10684416u    // [64][1024][64] bf16 (pre-scaled by log2(e))
#define WS_K      19073024u
#define WS_VT     27461632u    // [64][64][1024] bf16 (Vt[bh][d][n])
#define WS_Z      52627456u    // [8192][512] bf16

// ================= K0: weight transposes + BN fold =================
__global__ __launch_bounds__(256) void k0_setup(
    const float* Wk, const float* Wq, const float* Wv, const float* Wo,
    const float* gamma, const float* beta, const float* mean, const float* var,
    const float* relw, const float* relh, const float* Wout,
    u16* W1T, u16* WoT, u16* WoutT,
    u16* RWbf, u16* RHbf, float* scaleZ, float* shiftZ)
{
    int idx = blockIdx.x * 256 + threadIdx.x;
    if (idx < 786432) {
        int co = idx >> 9, c = idx & 511;
        int p = co >> 9, rem = co & 511;
        int h = rem >> 6, d = rem & 63;
        const float* src = (p == 0) ? Wq : (p == 1) ? Wk : Wv;
        W1T[idx] = f2bf(src[h * 32768 + c * 64 + d]);
    } else if (idx < 819200) {
        int r = idx - 786432;
        int h = r >> 12; int e = (r & 4095) >> 6, ep = r & 63;
        WoT[h * 4096 + ep * 64 + e] = f2bf(Wo[h * 4096 + e * 64 + ep]);
    } else if (idx < 1081344) {
        int r = idx - 819200;
        int c = r >> 9, co = r & 511;
        WoutT[co * 512 + c] = f2bf(Wout[c * 512 + co]);
    } else if (idx < 1145856) {
        int r = idx - 1081344;
        if (r < 32256) RWbf[r] = f2bf(relw[r]);
        else           RHbf[r - 32256] = f2bf(relh[r - 32256]);
    } else if (idx < 1146368) {
        int ch = idx - 1145856;
        float sc = gamma[ch] * rsqrtf(var[ch] + 1e-3f);
        scaleZ[ch] = sc;
        shiftZ[ch] = beta[ch] - mean[ch] * sc;
    }
}

__device__ __forceinline__ void packA(u16* dst, f32x4 a0, f32x4 a1, f32x4 a2, f32x4 a3){
    u32x4 v0 = { cvtpk(a0.x,a0.y), cvtpk(a0.z,a0.w), cvtpk(a1.x,a1.y), cvtpk(a1.z,a1.w) };
    u32x4 v1 = { cvtpk(a2.x,a2.y), cvtpk(a2.z,a2.w), cvtpk(a3.x,a3.y), cvtpk(a3.z,a3.w) };
    *(u32x4*)dst = v0;
    *(u32x4*)(dst + 8) = v1;
}

// ================= K1: fused QKV projection GEMM (reads f32 x directly) =========
// grid: 768 (XCD-swizzled); nt: 0-3 Q, 4-7 K, 8-11 V; Q scaled by log2(e)
// A and B both staged via double-buffered LDS (proven round-10 config).
__global__ __launch_bounds__(256, 3) void k1_gemm(
    const float* __restrict__ Xf, const u16* __restrict__ W1T,
    u16* Q, u16* K, u16* Vt)
{
    int s = blockIdx.x;
    int xcd = s & 7, r8 = s >> 3;
    int nt = r8 % 12, mt = (r8 / 12) * 8 + xcd;   // same-mt blocks share an XCD
    int tid = threadIdx.x;
    int w = tid >> 6, l = tid & 63, lg = l >> 4, ll = l & 15;
    int wm = w >> 1, wn = w & 1;
    int i0 = mt * 128, co0 = nt * 128;

    __shared__ __align__(16) u16 SM[20480];   // As[2][5120] | Bs[2][5120]
    u16* As = SM;
    u16* Bs = SM + 10240;

    int row = tid >> 1, c16 = (tid & 1) * 16;
    int st = row * 40 + c16;
    const float* ArowF = Xf + (size_t)(i0 + row) * 512 + c16;
    const u16*   Brow  = W1T + (size_t)(co0 + row) * 512 + c16;

    f32x4 acc[4][4];
#pragma unroll
    for (int m = 0; m < 4; m++)
#pragma unroll
        for (int nn = 0; nn < 4; nn++) acc[m][nn] = (f32x4){0,0,0,0};

    f32x4 ra0 = *(const f32x4*)&ArowF[0];
    f32x4 ra1 = *(const f32x4*)&ArowF[4];
    f32x4 ra2 = *(const f32x4*)&ArowF[8];
    f32x4 ra3 = *(const f32x4*)&ArowF[12];
    short8 rb0 = *(const short8*)&Brow[0];
    short8 rb1 = *(const short8*)&Brow[8];
    packA(&As[st], ra0, ra1, ra2, ra3);
    *(short8*)&Bs[st] = rb0; *(short8*)&Bs[st + 8] = rb1;
    __syncthreads();
    for (int ks = 0; ks < 16; ++ks) {
        int cur = ks & 1, nxt = cur ^ 1;
        if (ks < 15) {
            ra0 = *(const f32x4*)&ArowF[(ks + 1) * 32];
            ra1 = *(const f32x4*)&ArowF[(ks + 1) * 32 + 4];
            ra2 = *(const f32x4*)&ArowF[(ks + 1) * 32 + 8];
            ra3 = *(const f32x4*)&ArowF[(ks + 1) * 32 + 12];
            rb0 = *(const short8*)&Brow[(ks + 1) * 32];
            rb1 = *(const short8*)&Brow[(ks + 1) * 32 + 8];
        }
        const u16* Ab = As + cur * 5120;
        const u16* Bb = Bs + cur * 5120;
        short8 af[4], bfr[4];
#pragma unroll
        for (int m = 0; m < 4; m++)
            af[m] = *(const short8*)&Ab[(wm * 64 + m * 16 + ll) * 40 + lg * 8];
#pragma unroll
        for (int nn = 0; nn < 4; nn++)
            bfr[nn] = *(const short8*)&Bb[(wn * 64 + nn * 16 + ll) * 40 + lg * 8];
#pragma unroll
        for (int m = 0; m < 4; m++)
#pragma unroll
            for (int nn = 0; nn < 4; nn++)
                acc[m][nn] = MFMA(af[m], bfr[nn], acc[m][nn]);
        if (ks < 15) {
            int so = nxt * 5120 + st;
            packA(&As[so], ra0, ra1, ra2, ra3);
            *(short8*)&Bs[so] = rb0; *(short8*)&Bs[so + 8] = rb1;
        }
        __syncthreads();
    }

    int b = mt >> 3, nloc0 = (mt & 7) * 128;
    u16* Ts = SM;                        // [128][136] u16 = 34.8 KB
    if (nt < 8) {
        u16* dst = (nt < 4) ? Q : K;
        float qsc = (nt < 4) ? L2E : 1.0f;     // fold log2(e) into Q
        int coB = (nt & 3) * 128;
#pragma unroll
        for (int nn = 0; nn < 4; nn++)
#pragma unroll
            for (int m = 0; m < 4; m++)
#pragma unroll
                for (int r = 0; r < 4; r++)
                    Ts[(wm * 64 + m * 16 + lg * 4 + r) * 136 + wn * 64 + nn * 16 + ll]
                        = f2bf(acc[m][nn][r] * qsc);
        __syncthreads();
        int chunk = tid & 7;
#pragma unroll
        for (int j = 0; j < 8; j++) {
            int vr = j * 32 + (tid >> 3);
            int irow = vr >> 1, half = vr & 1;
            int hh = (coB >> 6) + half;
            u16* qdst = dst + ((size_t)(b * 8 + hh) * 1024 + nloc0 + irow) * 64;
            *(short8*)&qdst[chunk * 8] = *(const short8*)&Ts[irow * 136 + half * 64 + chunk * 8];
        }
    } else {
        // V tile: transpose via LDS -> Vt[bh][d][n]
#pragma unroll
        for (int nn = 0; nn < 4; nn++)
#pragma unroll
            for (int m = 0; m < 4; m++)
#pragma unroll
                for (int r = 0; r < 4; r++)
                    Ts[(wn * 64 + nn * 16 + ll) * 136 + wm * 64 + m * 16 + lg * 4 + r]
                        = f2bf(acc[m][nn][r]);
        __syncthreads();
        int co_l = tid >> 1, half = tid & 1;
        int co = (nt - 8) * 128 + co_l;
        int hh = (co >> 6) & 7, d = co & 63;
        u16* vdst = Vt + ((size_t)(b * 8 + hh) * 64 + d) * 1024 + nloc0 + half * 64;
#pragma unroll
        for (int j = 0; j < 8; j++)
            *(short8*)&vdst[j * 8] = *(const short8*)&Ts[co_l * 136 + half * 64 + j * 8];
    }
}

// ====== K2: flash attention, 32x32 MFMA, fused rel-logits (k1b absorbed) ========
// grid: 512 XCD-swizzled; block 256 (4 waves, 32 i-rows each)
__global__ __launch_bounds__(256, 2) void k2_attn(
    const u16* Q, const u16* K, const u16* Vt,
    const u16* relwb, const u16* relhb,
    const u16* WoT, const float* scaleZ, const float* shiftZ,
    u16* Z)
{
    int s_ = blockIdx.x;
    int xcd = s_ & 7, r8 = s_ >> 3;
    int it = r8 & 7, bh = (r8 >> 3) * 8 + xcd;    // 8 it-blocks of a bh share an XCD
    int b = bh >> 3, h = bh & 7;
    int tid = threadIdx.x;
    int wv = tid >> 6, l = tid & 63, il = l & 31, hf = l >> 5;
    int i0 = it * 128;
    int iw = i0 + wv * 32;

    __shared__ __align__(16) char smem[53760];
    u16*   Qs  = (u16*)smem;                 // [2][64][72] bf16
    u16*   Vs  = (u16*)(smem + 18432);       // [2][64][72] bf16
    float* rhS = (float*)(smem + 36864);     // [128][33] f32

    // K fragments: B[k=d][col=i], 4 k-slices of 16
    const u16* kb = K + ((size_t)bh * 1024 + iw) * 64;
    short8 kf0 = *(const short8*)&kb[il * 64 + hf * 8];
    short8 kf1 = *(const short8*)&kb[il * 64 + 16 + hf * 8];
    short8 kf2 = *(const short8*)&kb[il * 64 + 32 + hf * 8];
    short8 kf3 = *(const short8*)&kb[il * 64 + 48 + hf * 8];

    // ---- fused rel-logit prologue (replaces k1b kernel) ----
    float rw16[16];
    {
        float* wlb = (float*)(smem + wv * 8448);
        const u16* qsrc = Q + ((size_t)bh * 1024 + iw) * 64;
        short8 qa0 = *(const short8*)&qsrc[il * 64 + hf * 8];
        short8 qa1 = *(const short8*)&qsrc[il * 64 + 16 + hf * 8];
        short8 qa2 = *(const short8*)&qsrc[il * 64 + 32 + hf * 8];
        short8 qa3 = *(const short8*)&qsrc[il * 64 + 48 + hf * 8];
        int m1 = (32 + il > 62) ? 62 : 32 + il;   // col 63 never gathered
        const u16* rwsrc = relwb + h * 4032;
        const u16* rhsrc = relhb + h * 4032;
#pragma unroll
        for (int mt2 = 0; mt2 < 2; mt2++) {
            int m = mt2 ? m1 : il;
            short8 b0 = *(const short8*)&rwsrc[m * 64 + hf * 8];
            short8 b1 = *(const short8*)&rwsrc[m * 64 + 16 + hf * 8];
            short8 b2 = *(const short8*)&rwsrc[m * 64 + 32 + hf * 8];
            short8 b3 = *(const short8*)&rwsrc[m * 64 + 48 + hf * 8];
            f32x16 wa;
#pragma unroll
            for (int reg = 0; reg < 16; reg++) wa[reg] = 0.f;
            wa = MFMA32(qa0, b0, wa);
            wa = MFMA32(qa1, b1, wa);
            wa = MFMA32(qa2, b2, wa);
            wa = MFMA32(qa3, b3, wa);
#pragma unroll
            for (int reg = 0; reg < 16; reg++)
                wlb[((reg & 3) + 8 * (reg >> 2) + 4 * hf) * 66 + mt2 * 32 + il] = wa[reg];
        }
#pragma unroll
        for (int reg = 0; reg < 16; reg++) {
            int c = (reg & 3) + 8 * (reg >> 2) + 4 * hf;
            rw16[reg] = wlb[il * 65 + c + 31];      // il*66 + c + 31 - il
        }
#pragma unroll
        for (int mt2 = 0; mt2 < 2; mt2++) {
            int m = mt2 ? m1 : il;
            short8 b0 = *(const short8*)&rhsrc[m * 64 + hf * 8];
            short8 b1 = *(const short8*)&rhsrc[m * 64 + 16 + hf * 8];
            short8 b2 = *(const short8*)&rhsrc[m * 64 + 32 + hf * 8];
            short8 b3 = *(const short8*)&rhsrc[m * 64 + 48 + hf * 8];
            f32x16 ha;
#pragma unroll
            for (int reg = 0; reg < 16; reg++) ha[reg] = 0.f;
            ha = MFMA32(qa0, b0, ha);
            ha = MFMA32(qa1, b1, ha);
            ha = MFMA32(qa2, b2, ha);
            ha = MFMA32(qa3, b3, ha);
#pragma unroll
            for (int reg = 0; reg < 16; reg++)
                wlb[((reg & 3) + 8 * (reg >> 2) + 4 * hf) * 66 + mt2 * 32 + il] = ha[reg];
        }
        int x = iw >> 5;
#pragma unroll
        for (int reg = 0; reg < 16; reg++) {
            int c = (reg & 3) + 8 * (reg >> 2) + 4 * hf;
            rhS[(wv * 32 + il) * 33 + c] = wlb[il * 66 + c + 31 - x];
        }
    }
    __syncthreads();   // prologue scratch dead; staging area now safe

    f32x16 o0, o1;
#pragma unroll
    for (int reg = 0; reg < 16; reg++) { o0[reg] = 0.f; o1[reg] = 0.f; }
    float lsum = 0.f;

    const u16* qg = Q + (size_t)bh * 65536;
    const u16* vg = Vt + (size_t)bh * 65536;
    int srow = tid >> 2, sg = (tid & 3) * 8;   // 4 threads/row, granules sg, sg+32

    // prologue: chunk0 -> buf0; prefetch chunk1 into regs
    short8 pq0 = *(const short8*)&qg[(size_t)srow * 64 + sg];
    short8 pq1 = *(const short8*)&qg[(size_t)srow * 64 + sg + 32];
    short8 pv0 = *(const short8*)&vg[(size_t)srow * 1024 + sg];
    short8 pv1 = *(const short8*)&vg[(size_t)srow * 1024 + sg + 32];
    *(short8*)&Qs[srow * 72 + sg] = pq0;
    *(short8*)&Qs[srow * 72 + sg + 32] = pq1;
    *(short8*)&Vs[srow * 72 + sg] = pv0;
    *(short8*)&Vs[srow * 72 + sg + 32] = pv1;
    pq0 = *(const short8*)&qg[(size_t)(64 + srow) * 64 + sg];
    pq1 = *(const short8*)&qg[(size_t)(64 + srow) * 64 + sg + 32];
    pv0 = *(const short8*)&vg[(size_t)srow * 1024 + 64 + sg];
    pv1 = *(const short8*)&vg[(size_t)srow * 1024 + 64 + sg + 32];

    for (int ch = 0; ch < 16; ++ch) {
        int cur = ch & 1, nxt = cur ^ 1;
        barrier_lgkm();    // no vmcnt drain: keep ch+2 prefetch loads in flight
        if (ch < 15) {     // write chunk ch+1 into the other buffer
            *(short8*)&Qs[nxt * 4608 + srow * 72 + sg] = pq0;
            *(short8*)&Qs[nxt * 4608 + srow * 72 + sg + 32] = pq1;
            *(short8*)&Vs[nxt * 4608 + srow * 72 + sg] = pv0;
            *(short8*)&Vs[nxt * 4608 + srow * 72 + sg + 32] = pv1;
        }
        if (ch < 14) {     // issue chunk ch+2 loads
            int j2 = (ch + 2) * 64;
            pq0 = *(const short8*)&qg[(size_t)(j2 + srow) * 64 + sg];
            pq1 = *(const short8*)&qg[(size_t)(j2 + srow) * 64 + sg + 32];
            pv0 = *(const short8*)&vg[(size_t)srow * 1024 + j2 + sg];
            pv1 = *(const short8*)&vg[(size_t)srow * 1024 + j2 + sg + 32];
        }
        const u16* Qb = Qs + cur * 4608;
        const u16* Vb = Vs + cur * 4608;

#pragma unroll
        for (int u = 0; u < 2; ++u) {
            int jl = u * 32;
            float rhv = rhS[(wv * 32 + il) * 33 + ch * 2 + u];
            f32x16 sA;
#pragma unroll
            for (int reg = 0; reg < 16; reg++) sA[reg] = rw16[reg] + rhv;
            short8 aq0 = *(const short8*)&Qb[(jl + il) * 72 + hf * 8];
            short8 aq1 = *(const short8*)&Qb[(jl + il) * 72 + 16 + hf * 8];
            short8 aq2 = *(const short8*)&Qb[(jl + il) * 72 + 32 + hf * 8];
            short8 aq3 = *(const short8*)&Qb[(jl + il) * 72 + 48 + hf * 8];
            sA = MFMA32(aq0, kf0, sA);
            sA = MFMA32(aq1, kf1, sA);
            sA = MFMA32(aq2, kf2, sA);
            sA = MFMA32(aq3, kf3, sA);

            float p[16];
#pragma unroll
            for (int reg = 0; reg < 16; reg++) p[reg] = __builtin_amdgcn_exp2f(sA[reg]);
            {
                float t0 = (p[0] + p[1]) + (p[2] + p[3]);
                float t1 = (p[4] + p[5]) + (p[6] + p[7]);
                float t2 = (p[8] + p[9]) + (p[10] + p[11]);
                float t3 = (p[12] + p[13]) + (p[14] + p[15]);
                lsum += (t0 + t1) + (t2 + t3);
            }
            uint32_t W[8];
#pragma unroll
            for (int q = 0; q < 4; q++) {
                W[q * 2]     = cvtpk(p[q * 4 + 0], p[q * 4 + 1]);
                W[q * 2 + 1] = cvtpk(p[q * 4 + 2], p[q * 4 + 3]);
            }
            short8 pf0, pf1;
            {
                i32x2 rA = __builtin_amdgcn_permlane32_swap((int)W[0], (int)W[2], false, false);
                i32x2 rB = __builtin_amdgcn_permlane32_swap((int)W[1], (int)W[3], false, false);
                i32x4 t = { rA.x, rB.x, rA.y, rB.y };
                pf0 = *(short8*)&t;
            }
            {
                i32x2 rA = __builtin_amdgcn_permlane32_swap((int)W[4], (int)W[6], false, false);
                i32x2 rB = __builtin_amdgcn_permlane32_swap((int)W[5], (int)W[7], false, false);
                i32x4 t = { rA.x, rB.x, rA.y, rB.y };
                pf1 = *(short8*)&t;
            }

            __builtin_amdgcn_s_setprio(1);
            short8 av;
            av = *(const short8*)&Vb[il * 72 + jl + hf * 8];
            o0 = MFMA32(av, pf0, o0);
            av = *(const short8*)&Vb[(32 + il) * 72 + jl + hf * 8];
            o1 = MFMA32(av, pf0, o1);
            av = *(const short8*)&Vb[il * 72 + jl + 16 + hf * 8];
            o0 = MFMA32(av, pf1, o0);
            av = *(const short8*)&Vb[(32 + il) * 72 + jl + 16 + hf * 8];
            o1 = MFMA32(av, pf1, o1);
            __builtin_amdgcn_s_setprio(0);
        }
    }

    // total row-sum for col i=il: halves hf=0/1 cover disjoint j
    lsum += __shfl_xor(lsum, 32);
    float inv = 1.0f / lsum;
    __syncthreads();   // staging region reusable as per-wave O scratch

    u16* Ob = (u16*)smem + wv * 2304;      // [32][72] bf16, rows = i-local
#pragma unroll
    for (int q = 0; q < 4; q++) {
        uint32_t w0 = cvtpk(o0[q * 4 + 0] * inv, o0[q * 4 + 1] * inv);
        uint32_t w1 = cvtpk(o0[q * 4 + 2] * inv, o0[q * 4 + 3] * inv);
        *(uint32_t*)&Ob[il * 72 + q * 8 + hf * 4]     = w0;
        *(uint32_t*)&Ob[il * 72 + q * 8 + hf * 4 + 2] = w1;
        uint32_t w2 = cvtpk(o1[q * 4 + 0] * inv, o1[q * 4 + 1] * inv);
        uint32_t w3 = cvtpk(o1[q * 4 + 2] * inv, o1[q * 4 + 3] * inv);
        *(uint32_t*)&Ob[il * 72 + 32 + q * 8 + hf * 4]     = w2;
        *(uint32_t*)&Ob[il * 72 + 32 + q * 8 + hf * 4 + 2] = w3;
    }
    short8 ao0 = *(const short8*)&Ob[il * 72 + hf * 8];
    short8 ao1 = *(const short8*)&Ob[il * 72 + 16 + hf * 8];
    short8 ao2 = *(const short8*)&Ob[il * 72 + 32 + hf * 8];
    short8 ao3 = *(const short8*)&Ob[il * 72 + 48 + hf * 8];

    const u16* wob = WoT + h * 4096;
#pragma unroll
    for (int et = 0; et < 2; et++) {
        short8 bo0 = *(const short8*)&wob[(et * 32 + il) * 64 + hf * 8];
        short8 bo1 = *(const short8*)&wob[(et * 32 + il) * 64 + 16 + hf * 8];
        short8 bo2 = *(const short8*)&wob[(et * 32 + il) * 64 + 32 + hf * 8];
        short8 bo3 = *(const short8*)&wob[(et * 32 + il) * 64 + 48 + hf * 8];
        f32x16 zacc;
#pragma unroll
        for (int reg = 0; reg < 16; reg++) zacc[reg] = 0.f;
        zacc = MFMA32(ao0, bo0, zacc);
        zacc = MFMA32(ao1, bo1, zacc);
        zacc = MFMA32(ao2, bo2, zacc);
        zacc = MFMA32(ao3, bo3, zacc);
        int chn = h * 64 + et * 32 + il;
        float scv = scaleZ[chn], shv = shiftZ[chn];
#pragma unroll
        for (int reg = 0; reg < 16; reg++) {
            int i = iw + (reg & 3) + 8 * (reg >> 2) + 4 * hf;
            Z[((size_t)(b * 1024) + i) * 512 + chn] = f2bf(zacc[reg] * scv + shv);
        }
    }
}

// ================= K3: final 1x1 conv + residual (f32 out) =================
// grid: 1024, 64x64 tiles (XCD-swizzled): 4 blocks/CU, 16 waves/CU.
// LDS-staged double-buffer (proven round-10 config; LDS-free variant was +18us).
__global__ __launch_bounds__(256, 4) void k3_gemm(
    const u16* __restrict__ Zb, const u16* __restrict__ WoutT,
    const float* __restrict__ X, float* Y)
{
    int s = blockIdx.x;
    int xcd = s & 7, r8 = s >> 3;
    int nt = r8 & 7, mt = (r8 >> 3) * 8 + xcd;    // mt in [0,128), nt in [0,8)
    int tid = threadIdx.x;
    int w = tid >> 6, l = tid & 63, lg = l >> 4, ll = l & 15;
    int wm = w >> 1, wn = w & 1;
    int i0 = mt * 64, co0 = nt * 64;

    __shared__ __align__(16) u16 SM[10240];   // As[2][2560] | Bs[2][2560]
    u16* As = SM;
    u16* Bs = SM + 5120;

    int row = tid >> 2, c8 = (tid & 3) * 8;
    int st = row * 40 + c8;
    const u16* Arow = Zb + (size_t)(i0 + row) * 512 + c8;
    const u16* Brow = WoutT + (size_t)(co0 + row) * 512 + c8;

    f32x4 acc[2][2];
#pragma unroll
    for (int m = 0; m < 2; m++)
#pragma unroll
        for (int nn = 0; nn < 2; nn++) acc[m][nn] = (f32x4){0,0,0,0};

    short8 ra = *(const short8*)&Arow[0];
    short8 rb = *(const short8*)&Brow[0];
    *(short8*)&As[st] = ra;
    *(short8*)&Bs[st] = rb;
    __syncthreads();
    for (int ks = 0; ks < 16; ++ks) {
        int cur = ks & 1, nxt = cur ^ 1;
        if (ks < 15) {
            ra = *(const short8*)&Arow[(ks + 1) * 32];
            rb = *(const short8*)&Brow[(ks + 1) * 32];
        }
        const u16* Ab = As + cur * 2560;
        const u16* Bb = Bs + cur * 2560;
        short8 af[2], bfr[2];
#pragma unroll
        for (int m = 0; m < 2; m++)
            af[m] = *(const short8*)&Ab[(wm * 32 + m * 16 + ll) * 40 + lg * 8];
#pragma unroll
        for (int nn = 0; nn < 2; nn++)
            bfr[nn] = *(const short8*)&Bb[(wn * 32 + nn * 16 + ll) * 40 + lg * 8];
#pragma unroll
        for (int m = 0; m < 2; m++)
#pragma unroll
            for (int nn = 0; nn < 2; nn++)
                acc[m][nn] = MFMA(af[m], bfr[nn], acc[m][nn]);
        if (ks < 15) {
            int so = nxt * 2560 + st;
            *(short8*)&As[so] = ra;
            *(short8*)&Bs[so] = rb;
        }
        __syncthreads();
    }

#pragma unroll
    for (int m = 0; m < 2; m++)
#pragma unroll
        for (int nn = 0; nn < 2; nn++) {
            int i = i0 + wm * 32 + m * 16 + lg * 4;
            int co = co0 + wn * 32 + nn * 16 + ll;
#pragma unroll
            for (int r = 0; r < 4; r++) {
                size_t idx = (size_t)(i + r) * 512 + co;
                Y[idx] = acc[m][nn][r] + X[idx];
            }
        }
}

// ================= launch =================
extern "C" void kernel_launch(void* const* d_in, const int* in_sizes, int n_in,
                              void* d_out, int out_size, void* d_ws, size_t ws_size,
                              hipStream_t stream)
{
    const float* x     = (const float*)d_in[0];
    const float* Wk    = (const float*)d_in[1];
    const float* Wq    = (const float*)d_in[2];
    const float* Wv    = (const float*)d_in[3];
    const float* Wo    = (const float*)d_in[4];
    const float* gamma = (const float*)d_in[5];
    const float* beta  = (const float*)d_in[6];
    const float* mmean = (const float*)d_in[7];
    const float* mvar  = (const float*)d_in[8];
    const float* relw  = (const float*)d_in[9];
    const float* relh  = (const float*)d_in[10];
    const float* Wout  = (const float*)d_in[11];

    char* ws = (char*)d_ws;
    u16*   W1T    = (u16*)(ws + WS_W1T);
    u16*   WoT    = (u16*)(ws + WS_WOT);
    u16*   WoutT  = (u16*)(ws + WS_WOUTT);
    u16*   RWbf   = (u16*)(ws + WS_RELW);
    u16*   RHbf   = (u16*)(ws + WS_RELH);
    float* scaleZ = (float*)(ws + WS_SCALE);
    float* shiftZ = (float*)(ws + WS_SHIFT);
    u16*   Qw     = (u16*)(ws + WS_Q);
    u16*   Kw     = (u16*)(ws + WS_K);
    u16*   Vtw    = (u16*)(ws + WS_VT);
    u16*   Zw     = (u16*)(ws + WS_Z);

    k0_setup<<<4478, 256, 0, stream>>>(Wk, Wq, Wv, Wo, gamma, beta, mmean, mvar,
                                       relw, relh, Wout,
                                       W1T, WoT, WoutT, RWbf, RHbf,
                                       scaleZ, shiftZ);
    k1_gemm<<<768, 256, 0, stream>>>(x, W1T, Qw, Kw, Vtw);
    k2_attn<<<512, 256, 0, stream>>>(Qw, Kw, Vtw, RWbf, RHbf, WoT, scaleZ, shiftZ, Zw);
    k3_gemm<<<1024, 256, 0, stream>>>(Zw, WoutT, x, (float*)d_out);
}